// Round 1
// baseline (1391.321 us; speedup 1.0000x reference)
//
#include <hip/hip_runtime.h>
#include <math.h>

// D = 256 fixed by the reference. B (num segments) derived from out_size/2.
#define DIM 256

// Monotone float<->int mapping so signed-int atomicMax == float max.
// Involution: apply twice to get back.
__device__ __forceinline__ int enc_f(float f) {
    int i = __float_as_int(f);
    return i >= 0 ? i : (i ^ 0x7FFFFFFF);
}
__device__ __forceinline__ float dec_i(int i) {
    return __int_as_float(i >= 0 ? i : (i ^ 0x7FFFFFFF));
}

#define SEGMAX_INIT ((int)0x807FFFFF)  // below enc(-FLT_MAX); decodes to -inf

__global__ void init_small(int* __restrict__ segmax, float* __restrict__ S,
                           float* __restrict__ P, int B) {
    int t = blockIdx.x * blockDim.x + threadIdx.x;
    if (t < B) { segmax[t] = SEGMAX_INIT; S[t] = 0.0f; }
    if (t < 2 * B) P[t] = 0.0f;
}

// Pass 1: one wave per node-row. Lane l handles states[n][4l..4l+3].
// Stores gate[n], outs[n]; per-wave running segment max -> atomicMax on flush.
__global__ void __launch_bounds__(256) pass1(
    const float* __restrict__ states, const int* __restrict__ seg,
    const float* __restrict__ Wg, const float* __restrict__ bg,
    const float* __restrict__ Wo,
    float* __restrict__ gate, float2* __restrict__ outs,
    int* __restrict__ segmax, int N, int chunk)
{
    const int lane  = threadIdx.x & 63;
    const int gwave = (blockIdx.x * blockDim.x + threadIdx.x) >> 6;
    int start = gwave * chunk;
    if (start >= N) return;
    int end = min(N, start + chunk);

    // Per-lane weight fragments (coalesced one-time loads).
    const float4 wg  = *reinterpret_cast<const float4*>(Wg + lane * 4);
    const float4 woa = *reinterpret_cast<const float4*>(Wo + lane * 8);      // rows 4l,4l+1 (c0,c1 interleaved)
    const float4 wob = *reinterpret_cast<const float4*>(Wo + lane * 8 + 4);  // rows 4l+2,4l+3
    const float bgv = bg[0];

    int   runSeg = -1;
    float runMax = 0.0f;

    for (int n = start; n < end; ++n) {
        const float4 s4 = reinterpret_cast<const float4*>(states + (size_t)n * DIM)[lane];
        float g  = s4.x * wg.x  + s4.y * wg.y  + s4.z * wg.z  + s4.w * wg.w;
        float o0 = s4.x * woa.x + s4.y * woa.z + s4.z * wob.x + s4.w * wob.z;
        float o1 = s4.x * woa.y + s4.y * woa.w + s4.z * wob.y + s4.w * wob.w;
        #pragma unroll
        for (int m = 32; m >= 1; m >>= 1) {
            g  += __shfl_xor(g,  m, 64);
            o0 += __shfl_xor(o0, m, 64);
            o1 += __shfl_xor(o1, m, 64);
        }
        if (lane == 0) {
            g += bgv;
            gate[n] = g;
            outs[n] = make_float2(o0, o1);
            const int s = seg[n];
            if (s != runSeg) {
                if (runSeg >= 0) atomicMax(&segmax[runSeg], enc_f(runMax));
                runSeg = s;
                runMax = g;
            } else {
                runMax = fmaxf(runMax, g);
            }
        }
    }
    if (lane == 0 && runSeg >= 0) atomicMax(&segmax[runSeg], enc_f(runMax));
}

// Pass 2: thread-per-node over a contiguous per-wave chunk.
// Accumulates unnormalized S = sum(e), P = sum(e * out) per segment.
__global__ void __launch_bounds__(256) pass2(
    const int* __restrict__ seg, const float* __restrict__ gate,
    const float2* __restrict__ outs, const int* __restrict__ segmax,
    float* __restrict__ S, float* __restrict__ P, int N, int chunk)
{
    const int lane  = threadIdx.x & 63;
    const int gwave = (blockIdx.x * blockDim.x + threadIdx.x) >> 6;
    int start = gwave * chunk;
    if (start >= N) return;
    int end = min(N, start + chunk);

    int   runSeg = -1;
    float rS = 0.0f, rP0 = 0.0f, rP1 = 0.0f;

    for (int base = start; base < end; base += 64) {
        const int  n   = base + lane;
        const bool act = (n < end);
        const int  s_l = act ? seg[n] : 0;
        const int  s0  = __shfl(s_l, 0, 64);  // lane 0 always active (base < end)
        const bool uni = __all((!act) || (s_l == s0));

        if (uni) {
            float e = 0.0f, p0 = 0.0f, p1 = 0.0f;
            if (act) {
                float m = dec_i(segmax[s0]);
                if (!isfinite(m)) m = 0.0f;
                e = __expf(gate[n] - m);
                const float2 o = outs[n];
                p0 = e * o.x; p1 = e * o.y;
            }
            #pragma unroll
            for (int m = 32; m >= 1; m >>= 1) {
                e  += __shfl_xor(e,  m, 64);
                p0 += __shfl_xor(p0, m, 64);
                p1 += __shfl_xor(p1, m, 64);
            }
            if (lane == 0) {
                if (s0 != runSeg) {
                    if (runSeg >= 0) {
                        atomicAdd(&S[runSeg], rS);
                        atomicAdd(&P[2 * runSeg],     rP0);
                        atomicAdd(&P[2 * runSeg + 1], rP1);
                    }
                    runSeg = s0; rS = e; rP0 = p0; rP1 = p1;
                } else {
                    rS += e; rP0 += p0; rP1 += p1;
                }
            }
        } else {
            // Rare: segment boundary inside this 64-node window (<= 63 grid-wide).
            if (act) {
                float m = dec_i(segmax[s_l]);
                if (!isfinite(m)) m = 0.0f;
                const float e = __expf(gate[n] - m);
                const float2 o = outs[n];
                atomicAdd(&S[s_l], e);
                atomicAdd(&P[2 * s_l],     e * o.x);
                atomicAdd(&P[2 * s_l + 1], e * o.y);
            }
        }
    }
    if (lane == 0 && runSeg >= 0) {
        atomicAdd(&S[runSeg], rS);
        atomicAdd(&P[2 * runSeg],     rP0);
        atomicAdd(&P[2 * runSeg + 1], rP1);
    }
}

// pooled[b][c] = (P[b][c] + bo[c]*S[b]) / (S[b] + 1e-16)
__global__ void finalize(const float* __restrict__ S, const float* __restrict__ P,
                         const float* __restrict__ bo, float* __restrict__ out, int B) {
    int b = blockIdx.x * blockDim.x + threadIdx.x;
    if (b < B) {
        const float s = S[b];
        const float inv = 1.0f / (s + 1e-16f);
        out[2 * b]     = (P[2 * b]     + bo[0] * s) * inv;
        out[2 * b + 1] = (P[2 * b + 1] + bo[1] * s) * inv;
    }
}

extern "C" void kernel_launch(void* const* d_in, const int* in_sizes, int n_in,
                              void* d_out, int out_size, void* d_ws, size_t ws_size,
                              hipStream_t stream) {
    const float* states = (const float*)d_in[0];
    const int*   segs   = (const int*)d_in[1];
    const float* Wg     = (const float*)d_in[2];
    const float* bg     = (const float*)d_in[3];
    const float* Wo     = (const float*)d_in[4];
    const float* bo     = (const float*)d_in[5];
    float* out = (float*)d_out;

    const int N = in_sizes[0] / DIM;   // 1,000,000
    const int B = out_size / 2;        // 64

    // Workspace layout: gate[N] f32 | outs[N] float2 | segmax[B] i32 | S[B] f32 | P[2B] f32
    float*  gate   = (float*)d_ws;
    float2* outs   = (float2*)(gate + N);
    int*    segmax = (int*)(outs + N);
    float*  S      = (float*)(segmax + B);
    float*  P      = S + B;

    init_small<<<1, 256, 0, stream>>>(segmax, S, P, B);

    const int tpb = 256;
    {
        const int blocks = 2048;                       // 524288 threads = full occupancy fill
        const int waves  = blocks * (tpb / 64);
        const int chunk  = (N + waves - 1) / waves;    // contiguous rows per wave
        pass1<<<blocks, tpb, 0, stream>>>(states, segs, Wg, bg, Wo,
                                          gate, outs, segmax, N, chunk);
    }
    {
        const int blocks = 512;
        const int waves  = blocks * (tpb / 64);
        int chunk = (N + waves - 1) / waves;
        chunk = (chunk + 63) & ~63;                    // keep wave windows 64-aligned
        pass2<<<blocks, tpb, 0, stream>>>(segs, gate, outs, segmax, S, P, N, chunk);
    }
    finalize<<<1, 64, 0, stream>>>(S, P, bo, out, B);
}